// Round 1
// baseline (115.522 us; speedup 1.0000x reference)
//
#include <hip/hip_runtime.h>

#define NALL 1024
#define NH   512
#define NCOL 8
#define ROWS_PER_BLOCK 64
#define THREADS 256
#define CHUNKS (NALL / ROWS_PER_BLOCK)   // 16

// ---------------- kernel 1: normalize columns of concat(u,v) into w[1024][8] ----------------
__global__ void norm_kernel(const float* __restrict__ u, const float* __restrict__ v,
                            float* __restrict__ w) {
    __shared__ float red[THREADS];
    __shared__ float inv_norm[NCOL];
    const int tid = threadIdx.x;
    const int c = tid & 7;        // column
    const int chunk = tid >> 3;   // 0..31, each covers 32 rows of the 1024 concat rows

    float s = 0.f;
    const int rbeg = chunk * 32;
    for (int r = rbeg; r < rbeg + 32; ++r) {
        float val = (r < NH) ? u[r * NCOL + c] : v[(r - NH) * NCOL + c];
        s += val * val;
    }
    red[tid] = s;
    __syncthreads();
    // tree-reduce over chunks (stride multiples of 8 keep column congruence)
    for (int off = THREADS / 2; off >= NCOL; off >>= 1) {
        if (tid < off) red[tid] += red[tid + off];
        __syncthreads();
    }
    if (tid < NCOL) inv_norm[tid] = 1.0f / sqrtf(red[tid]);
    __syncthreads();

    for (int idx = tid; idx < NALL * NCOL; idx += THREADS) {
        int r = idx >> 3;
        int cc = idx & 7;
        float val = (r < NH) ? u[r * NCOL + cc] : v[(r - NH) * NCOL + cc];
        w[idx] = val * inv_norm[cc];
    }
}

// ---------------- kernel 2: main streaming quadratic-form reduction ----------------
// out[b][q*8+c], q = ih + 2*jh:
//   q0 = uJu (i<512, j<512), q1 = vJu (i>=512, j<512),
//   q2 = uJv (i<512, j>=512), q3 = vJv (i>=512, j>=512)
__global__ __launch_bounds__(THREADS) void jxy_kernel(
    const float* __restrict__ x, const float* __restrict__ w,
    float* __restrict__ out) {
    const int bid   = blockIdx.x;
    const int b     = bid >> 4;          // sample
    const int chunk = bid & (CHUNKS - 1);
    const int r0    = chunk * ROWS_PER_BLOCK;
    const int ih    = (r0 >= NH) ? 1 : 0;   // 64-row chunks never straddle halves

    const int tid  = threadIdx.x;
    const int wave = tid >> 6;
    const int lane = tid & 63;
    const int jbase = wave * 256 + lane * 4;   // this lane's 4 fixed j positions
    const int jh    = (jbase >= NH) ? 1 : 0;   // uniform per wave

    // stage this block's left-vector rows: w[r0 .. r0+64)[8] -> 2 KB LDS
    __shared__ __align__(16) float wl[ROWS_PER_BLOCK * NCOL];
    for (int idx = tid; idx < ROWS_PER_BLOCK * NCOL; idx += THREADS)
        wl[idx] = w[r0 * NCOL + idx];

    // right-vector fragment for this lane's 4 j's: 32 registers, reused for all rows
    float wr[4][NCOL];
#pragma unroll
    for (int k = 0; k < 4; ++k) {
        const float4* p = reinterpret_cast<const float4*>(w + (size_t)(jbase + k) * NCOL);
        float4 a = p[0];
        float4 bq = p[1];
        wr[k][0] = a.x;  wr[k][1] = a.y;  wr[k][2] = a.z;  wr[k][3] = a.w;
        wr[k][4] = bq.x; wr[k][5] = bq.y; wr[k][6] = bq.z; wr[k][7] = bq.w;
    }
    __syncthreads();

    float acc[NCOL];
#pragma unroll
    for (int c = 0; c < NCOL; ++c) acc[c] = 0.f;

    const float* xrow = x + ((size_t)b * NALL + r0) * NALL + jbase;

#pragma unroll 4
    for (int r = 0; r < ROWS_PER_BLOCK; ++r) {
        float4 xv = *reinterpret_cast<const float4*>(xrow + (size_t)r * NALL);

        float t[NCOL];
#pragma unroll
        for (int c = 0; c < NCOL; ++c)
            t[c] = fmaf(xv.x, wr[0][c],
                   fmaf(xv.y, wr[1][c],
                   fmaf(xv.z, wr[2][c],
                        xv.w * wr[3][c])));

        // wave-uniform broadcast reads from LDS (no bank conflict)
        float4 wa = *reinterpret_cast<const float4*>(&wl[r * NCOL]);
        float4 wb = *reinterpret_cast<const float4*>(&wl[r * NCOL + 4]);
        acc[0] = fmaf(wa.x, t[0], acc[0]);
        acc[1] = fmaf(wa.y, t[1], acc[1]);
        acc[2] = fmaf(wa.z, t[2], acc[2]);
        acc[3] = fmaf(wa.w, t[3], acc[3]);
        acc[4] = fmaf(wb.x, t[4], acc[4]);
        acc[5] = fmaf(wb.y, t[5], acc[5]);
        acc[6] = fmaf(wb.z, t[6], acc[6]);
        acc[7] = fmaf(wb.w, t[7], acc[7]);
    }

    // wave butterfly reduce (8 values x 6 steps)
#pragma unroll
    for (int c = 0; c < NCOL; ++c) {
#pragma unroll
        for (int off = 32; off >= 1; off >>= 1)
            acc[c] += __shfl_xor(acc[c], off, 64);
    }

    if (lane == 0) {
        const int q = ih + 2 * jh;
        float* o = out + (size_t)b * (4 * NCOL) + q * NCOL;
#pragma unroll
        for (int c = 0; c < NCOL; ++c)
            atomicAdd(o + c, acc[c]);
    }
}

extern "C" void kernel_launch(void* const* d_in, const int* in_sizes, int n_in,
                              void* d_out, int out_size, void* d_ws, size_t ws_size,
                              hipStream_t stream) {
    const float* x = (const float*)d_in[0];
    const float* u = (const float*)d_in[1];
    const float* v = (const float*)d_in[2];
    float* out = (float*)d_out;
    float* w   = (float*)d_ws;    // 1024*8 floats = 32 KB normalized table

    const int b_count = in_sizes[0] / (NALL * NALL);   // 128

    // zero the accumulated output every call (atomics accumulate into it)
    hipMemsetAsync(d_out, 0, (size_t)out_size * sizeof(float), stream);

    norm_kernel<<<1, THREADS, 0, stream>>>(u, v, w);

    dim3 grid(b_count * CHUNKS);
    jxy_kernel<<<grid, THREADS, 0, stream>>>(x, w, out);
}

// Round 3
// 100.864 us; speedup vs baseline: 1.1453x; 1.1453x over previous
//
#include <hip/hip_runtime.h>

#define NALL 1024
#define NH   512
#define NCOL 8
#define ROWS_PER_BLOCK 64
#define THREADS 256
#define CHUNKS (NALL / ROWS_PER_BLOCK)   // 16

typedef float f32x4 __attribute__((ext_vector_type(4)));

// Fused kernel: per-block recompute of the joint column norms of concat(u,v)
// (32 KB, L2/L3-resident -> ~free), then streaming quadratic-form reduction
// over this block's 64 rows of one sample's 1024x1024 Jacobian.
// out[b][q*8+c], q = ih + 2*jh:
//   q0 = uJu (i<512, j<512), q1 = vJu (i>=512, j<512),
//   q2 = uJv (i<512, j>=512), q3 = vJv (i>=512, j>=512)
__global__ __launch_bounds__(THREADS) void jxy_kernel(
    const float* __restrict__ x, const float* __restrict__ u,
    const float* __restrict__ v, float* __restrict__ out) {
    const int bid   = blockIdx.x;
    const int b     = bid >> 4;          // sample
    const int chunk = bid & (CHUNKS - 1);
    const int r0    = chunk * ROWS_PER_BLOCK;
    const int ih    = (r0 >= NH) ? 1 : 0;   // 64-row chunks never straddle halves
    const int rloc  = r0 - ih * NH;         // row offset within u or v

    const int tid  = threadIdx.x;
    const int wave = tid >> 6;
    const int lane = tid & 63;
    const int jbase = wave * 256 + lane * 4;   // this lane's 4 fixed j positions
    const int jh    = (jbase >= NH) ? 1 : 0;   // uniform per wave
    const int jloc  = jbase - jh * NH;

    // ---- phase 1: joint column norms of concat(u,v) ----
    __shared__ float red[THREADS];
    __shared__ float inv_norm[NCOL];
    {
        const int c   = tid & 7;
        const int seg = tid >> 3;    // 0..31
        float s = 0.f;
        for (int r = seg; r < NH; r += 32) {
            float a = u[r * NCOL + c];
            float bb = v[r * NCOL + c];
            s = fmaf(a, a, fmaf(bb, bb, s));
        }
        red[tid] = s;
        __syncthreads();
        for (int off = THREADS / 2; off >= NCOL; off >>= 1) {
            if (tid < off) red[tid] += red[tid + off];
            __syncthreads();
        }
        if (tid < NCOL) inv_norm[tid] = 1.0f / sqrtf(red[tid]);
        __syncthreads();
    }

    // ---- phase 2: stage normalized left rows (LDS) + right fragment (regs) ----
    __shared__ __align__(16) float wl[ROWS_PER_BLOCK * NCOL];
    const float* rawl = ih ? v : u;
    for (int idx = tid; idx < ROWS_PER_BLOCK * NCOL; idx += THREADS)
        wl[idx] = rawl[rloc * NCOL + idx] * inv_norm[idx & 7];

    const float* rawr = jh ? v : u;
    float wr[4][NCOL];
#pragma unroll
    for (int k = 0; k < 4; ++k) {
        const float4* p = reinterpret_cast<const float4*>(rawr + (size_t)(jloc + k) * NCOL);
        float4 a = p[0];
        float4 bq = p[1];
        wr[k][0] = a.x * inv_norm[0];  wr[k][1] = a.y * inv_norm[1];
        wr[k][2] = a.z * inv_norm[2];  wr[k][3] = a.w * inv_norm[3];
        wr[k][4] = bq.x * inv_norm[4]; wr[k][5] = bq.y * inv_norm[5];
        wr[k][6] = bq.z * inv_norm[6]; wr[k][7] = bq.w * inv_norm[7];
    }
    __syncthreads();

    // ---- phase 3: stream 64 rows of x (nontemporal: x >> L3, read once) ----
    float acc[NCOL];
#pragma unroll
    for (int c = 0; c < NCOL; ++c) acc[c] = 0.f;

    const float* xrow = x + ((size_t)b * NALL + r0) * NALL + jbase;

#pragma unroll 8
    for (int r = 0; r < ROWS_PER_BLOCK; ++r) {
        f32x4 xv = __builtin_nontemporal_load(
            reinterpret_cast<const f32x4*>(xrow + (size_t)r * NALL));

        float t[NCOL];
#pragma unroll
        for (int c = 0; c < NCOL; ++c)
            t[c] = fmaf(xv.x, wr[0][c],
                   fmaf(xv.y, wr[1][c],
                   fmaf(xv.z, wr[2][c],
                        xv.w * wr[3][c])));

        // wave-uniform broadcast reads from LDS (no bank conflict)
        float4 wa = *reinterpret_cast<const float4*>(&wl[r * NCOL]);
        float4 wb = *reinterpret_cast<const float4*>(&wl[r * NCOL + 4]);
        acc[0] = fmaf(wa.x, t[0], acc[0]);
        acc[1] = fmaf(wa.y, t[1], acc[1]);
        acc[2] = fmaf(wa.z, t[2], acc[2]);
        acc[3] = fmaf(wa.w, t[3], acc[3]);
        acc[4] = fmaf(wb.x, t[4], acc[4]);
        acc[5] = fmaf(wb.y, t[5], acc[5]);
        acc[6] = fmaf(wb.z, t[6], acc[6]);
        acc[7] = fmaf(wb.w, t[7], acc[7]);
    }

    // ---- phase 4: wave butterfly reduce (8 values x 6 steps) + one atomic set ----
#pragma unroll
    for (int c = 0; c < NCOL; ++c) {
#pragma unroll
        for (int off = 32; off >= 1; off >>= 1)
            acc[c] += __shfl_xor(acc[c], off, 64);
    }

    if (lane == 0) {
        const int q = ih + 2 * jh;
        float* o = out + (size_t)b * (4 * NCOL) + q * NCOL;
#pragma unroll
        for (int c = 0; c < NCOL; ++c)
            atomicAdd(o + c, acc[c]);
    }
}

extern "C" void kernel_launch(void* const* d_in, const int* in_sizes, int n_in,
                              void* d_out, int out_size, void* d_ws, size_t ws_size,
                              hipStream_t stream) {
    const float* x = (const float*)d_in[0];
    const float* u = (const float*)d_in[1];
    const float* v = (const float*)d_in[2];
    float* out = (float*)d_out;

    const int b_count = in_sizes[0] / (NALL * NALL);   // 128

    // zero the accumulated output every call (atomics accumulate into it)
    (void)hipMemsetAsync(d_out, 0, (size_t)out_size * sizeof(float), stream);

    dim3 grid(b_count * CHUNKS);
    jxy_kernel<<<grid, THREADS, 0, stream>>>(x, u, v, out);
}